// Round 5
// baseline (1751.224 us; speedup 1.0000x reference)
//
#include <hip/hip_runtime.h>

#define Nb 256
#define Tt 512
#define Dd 64
#define TD (Tt * Dd)

__device__ __forceinline__ float sigmoidf_(float x) { return 1.0f / (1.0f + __expf(-x)); }
__device__ __forceinline__ float tanhf_(float x) {
    x = fminf(fmaxf(x, -15.0f), 15.0f);
    float e = __expf(2.0f * x);
    return (e - 1.0f) / (e + 1.0f);
}
// Barrier that drains ONLY LDS (cross-wave data is LDS-only here).
__device__ __forceinline__ void bar_lds() {
    asm volatile("s_waitcnt lgkmcnt(0)\n\ts_barrier" ::: "memory");
}
// broadcast lane k's value to all lanes via SGPR (no LDS pipe traffic)
__device__ __forceinline__ float lanebc(float v, int k) {
    return __int_as_float(__builtin_amdgcn_readlane(__float_as_int(v), k));
}
// Opaque register pin: breaks the value's link to its defining load so LLVM
// cannot rematerialize the load inside the t-loop -- forces true residency.
__device__ __forceinline__ void pin_reg(float& x) {
    asm volatile("" : "+v"(x));
}
// dot-product accumulate: vector lane-distributed (lane k = v[k]), weights in VGPRs.
__device__ __forceinline__ void rlacc(float& a0, float& a1, float& a2, float& a3,
                                      float v, const float* __restrict__ w) {
#pragma unroll
    for (int k = 0; k < 64; k += 4) {
        a0 = fmaf(lanebc(v, k + 0), w[k + 0], a0);
        a1 = fmaf(lanebc(v, k + 1), w[k + 1], a1);
        a2 = fmaf(lanebc(v, k + 2), w[k + 2], a2);
        a3 = fmaf(lanebc(v, k + 3), w[k + 3], a3);
    }
}
// aux matvec: weights in LDS packed [kc][j][4] (contiguous 1KB per wave read ->
// conflict-free ds_read_b128); vector broadcast via readlane. Same k%4 interleave.
__device__ __forceinline__ void auxacc(float& a0, float& a1, float& a2, float& a3,
                                       float v, const float4* base, int j) {
#pragma unroll
    for (int kc = 0; kc < 16; ++kc) {
        float4 w4 = base[kc * 64 + j];
        a0 = fmaf(lanebc(v, 4 * kc + 0), w4.x, a0);
        a1 = fmaf(lanebc(v, 4 * kc + 1), w4.y, a1);
        a2 = fmaf(lanebc(v, 4 * kc + 2), w4.z, a2);
        a3 = fmaf(lanebc(v, 4 * kc + 3), w4.w, a3);
    }
}
// R1-proven flag primitives (atomic acquire/release, workgroup scope).
__device__ __forceinline__ void wait_flag(int* f, int want) {
    while (__hip_atomic_load(f, __ATOMIC_ACQUIRE, __HIP_MEMORY_SCOPE_WORKGROUP) < want) {}
    __builtin_amdgcn_sched_barrier(0);   // don't hoist dependent LDS reads above the poll
}
__device__ __forceinline__ void set_flag(int* f, int val) {
    asm volatile("s_waitcnt lgkmcnt(0)" ::: "memory");  // prior LDS writes committed
    __hip_atomic_store(f, val, __ATOMIC_RELEASE, __HIP_MEMORY_SCOPE_WORKGROUP);
}

// One block per batch row. 4 waves. z-path weights (wl/wu, 192 f32) PINNED in
// VGPRs via opaque asm (the allocator otherwise remats the global loads every
// timestep -> ~200KB/step/CU streamed from L2, the R1-R4 bottleneck: VGPR=188<192).
// Aux matrices (W_hist/W_gh/W_feat0diag/W_beta, 80KB) in LDS.
// Per step: ONE s_barrier. Intra-step deps via LDS flags:
//   w0: x_hat->x_c --fxc--> w2: z_hat->c_hat->c_c --fcc--> all (z finalize+LSTM)
//   w1: gamma_h(t+1), w3: beta(t+1) computed in their wait bubble (input-only deps).
__global__ __attribute__((amdgpu_flat_work_group_size(256, 256),
                          amdgpu_waves_per_eu(1, 1))) void rits_kernel(
    const float* __restrict__ inp,
    const float* __restrict__ W_hist, const float* __restrict__ b_hist,
    const float* __restrict__ W_feat, const float* __restrict__ b_feat,
    const float* __restrict__ W_gx,   const float* __restrict__ b_gx,
    const float* __restrict__ W_gh,   const float* __restrict__ b_gh,
    const float* __restrict__ W_beta, const float* __restrict__ b_beta,
    const float* __restrict__ W_lstm, const float* __restrict__ U_lstm,
    const float* __restrict__ b_lstm,
    const float* __restrict__ W_out,  const float* __restrict__ b_out,
    float* __restrict__ out)
{
    // aux weight tables: [w][kc][j][4], w = {hist, gh, feat(0-diag), beta_lo, beta_hi}
    __shared__ __align__(16) float4 s_aux[5 * 1024];
    __shared__ __align__(16) float s_h[2][64];
    __shared__ __align__(16) float s_m[2][64];
    __shared__ __align__(16) float s_x[2][64];
    __shared__ __align__(16) float s_d[2][64];
    __shared__ __align__(16) float s_gx[2][64];
    __shared__ __align__(16) float s_gh[2][64];
    __shared__ __align__(16) float s_bt[2][64];
    __shared__ __align__(16) float s_xc[64];
    __shared__ __align__(16) float s_xh[64];
    __shared__ __align__(16) float s_cc[64];
    __shared__ int s_fstage;   // staged-through step index + 1
    __shared__ int s_fxc;      // x_c for step t ready  (value t+1)
    __shared__ int s_fcc;      // c_c for step t ready  (value t+1)

    const int tid  = threadIdx.x;
    const int wave = tid >> 6;
    const int j    = tid & 63;
    const int jl   = j & 15;
    const int gate = j >> 4;
    const int n    = blockIdx.x;
    const int col  = (gate << 6) + (wave << 4) + jl;

    // ---- fill aux tables (one-time; weights L2/L3-hot across blocks) ----
    for (int e = tid; e < 5 * 1024; e += 256) {
        int w  = e >> 10;
        int idx = e & 1023;
        int kc = idx >> 6, jj = idx & 63;
        const float* M = (w == 0) ? W_hist : (w == 1) ? W_gh
                       : (w == 2) ? W_feat : W_beta;
        int k0 = 4 * kc + ((w == 4) ? 64 : 0);
        float4 v;
        v.x = M[(k0 + 0) * 64 + jj];
        v.y = M[(k0 + 1) * 64 + jj];
        v.z = M[(k0 + 2) * 64 + jj];
        v.w = M[(k0 + 3) * 64 + jj];
        if (w == 2) {  // ZeroDiagonalConstraint on W_feat
            if (4 * kc + 0 == jj) v.x = 0.0f;
            if (4 * kc + 1 == jj) v.y = 0.0f;
            if (4 * kc + 2 == jj) v.z = 0.0f;
            if (4 * kc + 3 == jj) v.w = 0.0f;
        }
        s_aux[e] = v;
    }
    const float4* auxw = s_aux + (size_t)wave * 1024;   // wave's primary matrix
    const float4* auxb = s_aux + (size_t)4 * 1024;      // beta hi-half (wave 3)

    // ---- register-resident z-path weights, pinned against remat ----
    float wl[128], wu[64];
#pragma unroll
    for (int k = 0; k < 128; ++k) { wl[k] = W_lstm[k * 256 + col]; pin_reg(wl[k]); }
#pragma unroll
    for (int k = 0; k < 64; ++k)  { wu[k] = U_lstm[k * 256 + col]; pin_reg(wu[k]); }
    const float bl = b_lstm[col];

    const float bwv = (wave == 0) ? b_hist[j] : (wave == 1) ? b_gh[j]
                    : (wave == 2) ? b_feat[j] : b_beta[j];

    float gxw = 0, gxb = 0, wout = 0, bo = 0;
    if (wave == 0) {
        gxw = W_gx[j * 64 + j]; gxb = b_gx[j];
        wout = W_out[j]; bo = b_out[0];
    }

    const size_t base = (size_t)n * (3 * TD);
    float cx = 0, cm = 0, nx = 0, nm = 0, nd = 0;
    float c = 0.0f;

    // ---- prologue: flags, h0, stage t=0, prefetch t=1 ----
    if (wave == 0) {
        s_fstage = 0; s_fxc = 0; s_fcc = 0;
        cx = inp[base + j]; cm = inp[base + TD + j];
        float cd = inp[base + 2 * TD + j];
        s_x[0][j] = cx; s_m[0][j] = cm; s_d[0][j] = cd;
        s_gx[0][j] = __expf(-fmaxf(fmaf(cd, gxw, gxb), 0.0f));
        nx = inp[base + Dd + j];
        nm = inp[base + TD + Dd + j];
        nd = inp[base + 2 * TD + Dd + j];
    } else if (wave == 1) {
        s_h[0][j] = 0.0f;
    }
    bar_lds();
    // gamma_h(0) and beta(0) from staged t=0 inputs
    if (wave == 1) {
        float a0 = 0, a1 = 0, a2 = 0, a3 = 0;
        auxacc(a0, a1, a2, a3, s_d[0][j], auxw, j);
        s_gh[0][j] = __expf(-fmaxf(bwv + ((a0 + a1) + (a2 + a3)), 0.0f));
    } else if (wave == 3) {
        float a0 = 0, a1 = 0, a2 = 0, a3 = 0;
        auxacc(a0, a1, a2, a3, s_gx[0][j], auxw, j);
        auxacc(a0, a1, a2, a3, s_m[0][j], auxb, j);
        s_bt[0][j] = sigmoidf_(bwv + ((a0 + a1) + (a2 + a3)));
    }
    bar_lds();

#pragma unroll 1
    for (int t = 0; t < Tt; ++t) {
        const int buf = t & 1, nbuf = buf ^ 1;
        // lane-distributed vectors for this step (1 ds_read_b32 each)
        float hreg  = s_h[buf][j];
        float ghreg = s_gh[buf][j];
        float mreg  = s_m[buf][j];
        float z0 = 0, z1 = 0, z2 = 0, z3 = 0;

        if (wave == 0) {
            // x_hat first: unblocks wave 2's chain
            float a0 = 0, a1 = 0, a2 = 0, a3 = 0;
            auxacc(a0, a1, a2, a3, hreg, auxw, j);
            float acc = bwv + ((a0 + a1) + (a2 + a3));
            s_xh[j] = acc;
            s_xc[j] = fmaf(cm, cx, (1.0f - cm) * acc);
            set_flag(&s_fxc, t + 1);
            out[(size_t)((n * 3 + 0) * Tt + t) * Dd + j] = acc;
            // stage t+1, prefetch t+2
            if (t + 1 < Tt) {
                s_x[nbuf][j] = nx; s_m[nbuf][j] = nm; s_d[nbuf][j] = nd;
                s_gx[nbuf][j] = __expf(-fmaxf(fmaf(nd, gxw, gxb), 0.0f));
                set_flag(&s_fstage, t + 2);
                cx = nx; cm = nm;
                if (t + 2 < Tt) {
                    nx = inp[base + (t + 2) * Dd + j];
                    nm = inp[base + TD + (t + 2) * Dd + j];
                    nd = inp[base + 2 * TD + (t + 2) * Dd + j];
                }
            }
        }

        // ---- common z partials: m-part + U-part (hp = h*gamma_h, per-lane) ----
        rlacc(z0, z1, z2, z3, mreg, wl + 64);
        rlacc(z0, z1, z2, z3, hreg * ghreg, wu);

        if (wave == 2) {
            wait_flag(&s_fxc, t + 1);
            float a0 = 0, a1 = 0, a2 = 0, a3 = 0;
            auxacc(a0, a1, a2, a3, s_xc[j], auxw, j);
            float acc = bwv + ((a0 + a1) + (a2 + a3));
            float bt  = s_bt[buf][j];
            float chat = bt * acc + (1.0f - bt) * s_xh[j];
            float xj  = s_x[buf][j];
            float ccj = fmaf(mreg, xj, (1.0f - mreg) * chat);
            s_cc[j] = ccj;
            set_flag(&s_fcc, t + 1);
            out[(size_t)((n * 3 + 1) * Tt + t) * Dd + j] = acc;
            out[(size_t)((n * 3 + 2) * Tt + t) * Dd + j] = chat;
        } else if (wave == 1) {
            if (t + 1 < Tt) {  // gamma_h for t+1 (input-only dep) in the wait bubble
                wait_flag(&s_fstage, t + 2);
                float a0 = 0, a1 = 0, a2 = 0, a3 = 0;
                auxacc(a0, a1, a2, a3, s_d[nbuf][j], auxw, j);
                s_gh[nbuf][j] = __expf(-fmaxf(bwv + ((a0 + a1) + (a2 + a3)), 0.0f));
            }
        } else if (wave == 3) {
            if (t + 1 < Tt) {  // beta for t+1 (input-only dep) in the wait bubble
                wait_flag(&s_fstage, t + 2);
                float a0 = 0, a1 = 0, a2 = 0, a3 = 0;
                auxacc(a0, a1, a2, a3, s_gx[nbuf][j], auxw, j);
                auxacc(a0, a1, a2, a3, s_m[nbuf][j], auxb, j);
                s_bt[nbuf][j] = sigmoidf_(bwv + ((a0 + a1) + (a2 + a3)));
            }
        }

        // ---- z finalize + in-wave LSTM ----
        wait_flag(&s_fcc, t + 1);
        rlacc(z0, z1, z2, z3, s_cc[j], wl);
        float z = bl + ((z0 + z1) + (z2 + z3));
        float zi = __shfl(z, jl, 64);
        float zf = __shfl(z, 16 + jl, 64);
        float zg = __shfl(z, 32 + jl, 64);
        float zo = __shfl(z, 48 + jl, 64);
        c = sigmoidf_(zf) * c + sigmoidf_(zi) * tanhf_(zg);
        float hn = sigmoidf_(zo) * tanhf_(c);
        if (gate == 0) s_h[nbuf][(wave << 4) + jl] = hn;
        bar_lds();   // the ONLY barrier per step: h/gh/bt/staged-input hand-off
    }

    // final prediction: sigmoid(h_last @ W_out + b_out)
    if (wave == 0) {
        float p = s_h[Tt & 1][j] * wout;
#pragma unroll
        for (int off = 32; off > 0; off >>= 1) p += __shfl_down(p, off, 64);
        if (j == 0) out[(size_t)Nb * 3 * TD + n] = sigmoidf_(p + bo);
    }
}

extern "C" void kernel_launch(void* const* d_in, const int* in_sizes, int n_in,
                              void* d_out, int out_size, void* d_ws, size_t ws_size,
                              hipStream_t stream) {
    (void)in_sizes; (void)n_in; (void)out_size; (void)d_ws; (void)ws_size;
    const float* inp    = (const float*)d_in[0];
    const float* W_hist = (const float*)d_in[1];
    const float* b_hist = (const float*)d_in[2];
    const float* W_feat = (const float*)d_in[3];
    const float* b_feat = (const float*)d_in[4];
    const float* W_gx   = (const float*)d_in[5];
    const float* b_gx   = (const float*)d_in[6];
    const float* W_gh   = (const float*)d_in[7];
    const float* b_gh   = (const float*)d_in[8];
    const float* W_beta = (const float*)d_in[9];
    const float* b_beta = (const float*)d_in[10];
    const float* W_lstm = (const float*)d_in[11];
    const float* U_lstm = (const float*)d_in[12];
    const float* b_lstm = (const float*)d_in[13];
    const float* W_out  = (const float*)d_in[14];
    const float* b_out  = (const float*)d_in[15];
    float* out = (float*)d_out;

    rits_kernel<<<dim3(Nb), dim3(256), 0, stream>>>(
        inp, W_hist, b_hist, W_feat, b_feat, W_gx, b_gx, W_gh, b_gh,
        W_beta, b_beta, W_lstm, U_lstm, b_lstm, W_out, b_out, out);
}

// Round 6
// 1396.586 us; speedup vs baseline: 1.2539x; 1.2539x over previous
//
#include <hip/hip_runtime.h>

#define Nb 256
#define Tt 512
#define Dd 64
#define TD (Tt * Dd)

__device__ __forceinline__ float sigmoidf_(float x) { return 1.0f / (1.0f + __expf(-x)); }
__device__ __forceinline__ float tanhf_(float x) {
    x = fminf(fmaxf(x, -15.0f), 15.0f);
    float e = __expf(2.0f * x);
    return (e - 1.0f) / (e + 1.0f);
}
// Barrier that drains ONLY LDS (cross-wave data is LDS-only here).
__device__ __forceinline__ void bar_lds() {
    asm volatile("s_waitcnt lgkmcnt(0)\n\ts_barrier" ::: "memory");
}
// broadcast lane k's value to all lanes via SGPR (no LDS pipe traffic)
__device__ __forceinline__ float lanebc(float v, int k) {
    return __int_as_float(__builtin_amdgcn_readlane(__float_as_int(v), k));
}
// K-slice dot-product accumulate: vector lane-distributed (lane k = v[k]),
// KB = readlane base (wave-uniform, compile-time), KN weights per lane.
template <int KB, int KN>
__device__ __forceinline__ void rlk(float& a0, float& a1, float& a2, float& a3,
                                    float v, const float* __restrict__ w) {
#pragma unroll
    for (int k = 0; k < KN; k += 4) {
        a0 = fmaf(lanebc(v, KB + k + 0), w[k + 0], a0);
        a1 = fmaf(lanebc(v, KB + k + 1), w[k + 1], a1);
        a2 = fmaf(lanebc(v, KB + k + 2), w[k + 2], a2);
        a3 = fmaf(lanebc(v, KB + k + 3), w[k + 3], a3);
    }
}
// R1-proven flag primitives (atomic acquire/release, workgroup scope).
__device__ __forceinline__ void wait_flag(int* f, int want) {
    while (__hip_atomic_load(f, __ATOMIC_ACQUIRE, __HIP_MEMORY_SCOPE_WORKGROUP) < want) {}
    __builtin_amdgcn_sched_barrier(0);
}
__device__ __forceinline__ void set_flag(int* f, int val) {
    asm volatile("s_waitcnt lgkmcnt(0)" ::: "memory");
    __hip_atomic_store(f, val, __ATOMIC_RELEASE, __HIP_MEMORY_SCOPE_WORKGROUP);
}

// One block per batch row, 8 waves (512 thr). K-split across wave pairs so
// per-thread weights = 128-160 floats -> genuinely register-resident (the
// R1-R5 bottleneck: 256-320/thread demand forced remat/spill reloads of
// ~100KB/step from L2; allocator capped at 148-188 VGPRs regardless of hints).
//   primaries w0-w3: z rows 0-95 (cc+m_lo) + aux LO half + LSTM finalize
//   helpers  w4-w7: z rows 96-191 (m_hi+U) + aux HI half; w4 stages inputs
// Combine via LDS partials + R1 atomic flags. ONE s_barrier per step.
__global__ __attribute__((amdgpu_flat_work_group_size(512, 512),
                          amdgpu_waves_per_eu(2, 2))) void rits_kernel(
    const float* __restrict__ inp,
    const float* __restrict__ W_hist, const float* __restrict__ b_hist,
    const float* __restrict__ W_feat, const float* __restrict__ b_feat,
    const float* __restrict__ W_gx,   const float* __restrict__ b_gx,
    const float* __restrict__ W_gh,   const float* __restrict__ b_gh,
    const float* __restrict__ W_beta, const float* __restrict__ b_beta,
    const float* __restrict__ W_lstm, const float* __restrict__ U_lstm,
    const float* __restrict__ b_lstm,
    const float* __restrict__ W_out,  const float* __restrict__ b_out,
    float* __restrict__ out)
{
    __shared__ __align__(16) float s_h[2][64], s_m[2][64], s_x[2][64], s_d[2][64];
    __shared__ __align__(16) float s_gx[2][64], s_gh[2][64], s_bt[2][64];
    __shared__ __align__(16) float s_xh[64], s_xc[64], s_cc[64];
    __shared__ __align__(16) float s_xhp[64], s_ghp[64], s_zhp[64], s_bhp[64];
    __shared__ __align__(16) float s_zpart[4][64];
    __shared__ int s_fstage, s_fxp, s_fxc, s_fzhp, s_fcc, s_fghp, s_fbhp, s_fz[4];

    const int tid  = threadIdx.x;
    const int wave = tid >> 6;
    const int l    = tid & 63;
    const int p    = wave & 3;        // z column-pair id (primary/helper share)
    const bool helper = wave >= 4;
    const int jl   = l & 15;
    const int gate = l >> 4;
    const int n    = blockIdx.x;
    const int col  = (gate << 6) + (p << 4) + jl;   // z column owned by pair p

    // ---- z-path weights: 96 floats per thread ----
    float wz1[64], wz2[32];
    if (!helper) {
#pragma unroll
        for (int k = 0; k < 64; ++k) wz1[k] = W_lstm[k * 256 + col];          // cc rows
#pragma unroll
        for (int k = 0; k < 32; ++k) wz2[k] = W_lstm[(64 + k) * 256 + col];   // m 0-31
    } else {
#pragma unroll
        for (int k = 0; k < 64; ++k) wz1[k] = U_lstm[k * 256 + col];          // U rows
#pragma unroll
        for (int k = 0; k < 32; ++k) wz2[k] = W_lstm[(96 + k) * 256 + col];   // m 32-63
    }
    const float bl = helper ? 0.0f : b_lstm[col];

    // ---- aux weights: 32 per thread (64 for beta waves 3/7) ----
    float wa[64];
    if (wave == 0) {
#pragma unroll
        for (int k = 0; k < 32; ++k) wa[k] = W_hist[k * 64 + l];
    } else if (wave == 5) {
#pragma unroll
        for (int k = 0; k < 32; ++k) wa[k] = W_hist[(32 + k) * 64 + l];
    } else if (wave == 1) {
#pragma unroll
        for (int k = 0; k < 32; ++k) wa[k] = W_gh[k * 64 + l];
    } else if (wave == 4) {
#pragma unroll
        for (int k = 0; k < 32; ++k) wa[k] = W_gh[(32 + k) * 64 + l];
    } else if (wave == 2) {
#pragma unroll
        for (int k = 0; k < 32; ++k) wa[k] = (k == l) ? 0.0f : W_feat[k * 64 + l];
    } else if (wave == 6) {
#pragma unroll
        for (int k = 0; k < 32; ++k) wa[k] = ((32 + k) == l) ? 0.0f : W_feat[(32 + k) * 64 + l];
    } else if (wave == 3) {
#pragma unroll
        for (int k = 0; k < 64; ++k) wa[k] = W_beta[k * 64 + l];              // gamma_x rows
    } else {  // wave 7
#pragma unroll
        for (int k = 0; k < 64; ++k) wa[k] = W_beta[(64 + k) * 64 + l];       // m rows
    }
    const float bwv = (wave == 0) ? b_hist[l] : (wave == 1) ? b_gh[l]
                    : (wave == 2) ? b_feat[l] : (wave == 3) ? b_beta[l] : 0.0f;

    float gxw = 0, gxb = 0, wout = 0, bo = 0;
    if (wave == 4) { gxw = W_gx[l * 64 + l]; gxb = b_gx[l]; }
    if (wave == 0) { wout = W_out[l]; bo = b_out[0]; }

    const size_t base = (size_t)n * (3 * TD);
    float nx = 0, nm = 0, nd = 0;
    float c = 0.0f;

    // ---- prologue ----
    if (tid == 0) {
        s_fstage = 0; s_fxp = 0; s_fxc = 0; s_fzhp = 0; s_fcc = 0;
        s_fghp = 0; s_fbhp = 0;
        s_fz[0] = 0; s_fz[1] = 0; s_fz[2] = 0; s_fz[3] = 0;
    }
    if (wave == 4) {
        float x0 = inp[base + l], m0 = inp[base + TD + l], d0 = inp[base + 2 * TD + l];
        s_x[0][l] = x0; s_m[0][l] = m0; s_d[0][l] = d0;
        s_gx[0][l] = __expf(-fmaxf(fmaf(d0, gxw, gxb), 0.0f));
        nx = inp[base + Dd + l];
        nm = inp[base + TD + Dd + l];
        nd = inp[base + 2 * TD + Dd + l];
    }
    if (wave == 0) s_h[0][l] = 0.0f;
    bar_lds();
    // gamma_h(0) and beta(0)
    if (wave == 4) {
        float a0 = 0, a1 = 0, a2 = 0, a3 = 0;
        rlk<32, 32>(a0, a1, a2, a3, s_d[0][l], wa);
        s_ghp[l] = (a0 + a1) + (a2 + a3);
        set_flag(&s_fghp, 1);
    } else if (wave == 1) {
        float a0 = 0, a1 = 0, a2 = 0, a3 = 0;
        rlk<0, 32>(a0, a1, a2, a3, s_d[0][l], wa);
        wait_flag(&s_fghp, 1);
        s_gh[0][l] = __expf(-fmaxf(bwv + (a0 + a1) + (a2 + a3) + s_ghp[l], 0.0f));
    } else if (wave == 7) {
        float a0 = 0, a1 = 0, a2 = 0, a3 = 0;
        rlk<0, 64>(a0, a1, a2, a3, s_m[0][l], wa);
        s_bhp[l] = (a0 + a1) + (a2 + a3);
        set_flag(&s_fbhp, 1);
    } else if (wave == 3) {
        float a0 = 0, a1 = 0, a2 = 0, a3 = 0;
        rlk<0, 64>(a0, a1, a2, a3, s_gx[0][l], wa);
        wait_flag(&s_fbhp, 1);
        s_bt[0][l] = sigmoidf_(bwv + (a0 + a1) + (a2 + a3) + s_bhp[l]);
    }
    bar_lds();

#pragma unroll 1
    for (int t = 0; t < Tt; ++t) {
        const int buf = t & 1, nbuf = buf ^ 1;
        float hreg  = s_h[buf][l];
        float ghreg = s_gh[buf][l];
        float mreg  = s_m[buf][l];
        float hp    = hreg * ghreg;
        float z0 = 0, z1 = 0, z2 = 0, z3 = 0;

        if (wave == 4) {
            if (t + 1 < Tt) {   // stage t+1 (unblocks bubble waves), gh-hi(t+1)
                s_x[nbuf][l] = nx; s_m[nbuf][l] = nm; s_d[nbuf][l] = nd;
                s_gx[nbuf][l] = __expf(-fmaxf(fmaf(nd, gxw, gxb), 0.0f));
                set_flag(&s_fstage, t + 2);
                float a0 = 0, a1 = 0, a2 = 0, a3 = 0;
                rlk<32, 32>(a0, a1, a2, a3, nd, wa);
                s_ghp[l] = (a0 + a1) + (a2 + a3);
                set_flag(&s_fghp, t + 2);
            }
            rlk<32, 32>(z0, z1, z2, z3, mreg, wz2);
            rlk<0, 64>(z0, z1, z2, z3, hp, wz1);
            s_zpart[0][l] = (z0 + z1) + (z2 + z3);
            set_flag(&s_fz[0], t + 1);
            if (t + 2 < Tt) {
                nx = inp[base + (t + 2) * Dd + l];
                nm = inp[base + TD + (t + 2) * Dd + l];
                nd = inp[base + 2 * TD + (t + 2) * Dd + l];
            }
        } else if (wave == 5) {
            float a0 = 0, a1 = 0, a2 = 0, a3 = 0;     // x_hat hi first: w0 needs it early
            rlk<32, 32>(a0, a1, a2, a3, hreg, wa);
            s_xhp[l] = (a0 + a1) + (a2 + a3);
            set_flag(&s_fxp, t + 1);
            rlk<32, 32>(z0, z1, z2, z3, mreg, wz2);
            rlk<0, 64>(z0, z1, z2, z3, hp, wz1);
            s_zpart[1][l] = (z0 + z1) + (z2 + z3);
            set_flag(&s_fz[1], t + 1);
        } else if (wave == 6) {
            wait_flag(&s_fxc, t + 1);                 // z_hat hi (w2 blocks on it)
            float xcv = s_xc[l];
            float a0 = 0, a1 = 0, a2 = 0, a3 = 0;
            rlk<32, 32>(a0, a1, a2, a3, xcv, wa);
            s_zhp[l] = (a0 + a1) + (a2 + a3);
            set_flag(&s_fzhp, t + 1);
            rlk<32, 32>(z0, z1, z2, z3, mreg, wz2);
            rlk<0, 64>(z0, z1, z2, z3, hp, wz1);
            s_zpart[2][l] = (z0 + z1) + (z2 + z3);
            set_flag(&s_fz[2], t + 1);
        } else if (wave == 7) {
            rlk<32, 32>(z0, z1, z2, z3, mreg, wz2);
            rlk<0, 64>(z0, z1, z2, z3, hp, wz1);
            s_zpart[3][l] = (z0 + z1) + (z2 + z3);
            set_flag(&s_fz[3], t + 1);
            if (t + 1 < Tt) {                          // beta-hi(t+1) in bubble
                wait_flag(&s_fstage, t + 2);
                float mnb = s_m[nbuf][l];
                float a0 = 0, a1 = 0, a2 = 0, a3 = 0;
                rlk<0, 64>(a0, a1, a2, a3, mnb, wa);
                s_bhp[l] = (a0 + a1) + (a2 + a3);
                set_flag(&s_fbhp, t + 2);
            }
        } else {
            // ---- primaries ----
            if (wave == 0) {
                float xreg = s_x[buf][l];
                float a0 = 0, a1 = 0, a2 = 0, a3 = 0;
                rlk<0, 32>(a0, a1, a2, a3, hreg, wa);
                wait_flag(&s_fxp, t + 1);
                float xh = bwv + (a0 + a1) + (a2 + a3) + s_xhp[l];
                float xc = fmaf(mreg, xreg, (1.0f - mreg) * xh);
                s_xh[l] = xh; s_xc[l] = xc;
                set_flag(&s_fxc, t + 1);
                out[(size_t)((n * 3 + 0) * Tt + t) * Dd + l] = xh;
                rlk<0, 32>(z0, z1, z2, z3, mreg, wz2);
            } else if (wave == 1) {
                rlk<0, 32>(z0, z1, z2, z3, mreg, wz2);
                if (t + 1 < Tt) {                      // gamma_h(t+1) in bubble
                    wait_flag(&s_fstage, t + 2);
                    float dnb = s_d[nbuf][l];
                    float a0 = 0, a1 = 0, a2 = 0, a3 = 0;
                    rlk<0, 32>(a0, a1, a2, a3, dnb, wa);
                    wait_flag(&s_fghp, t + 2);
                    s_gh[nbuf][l] = __expf(-fmaxf(bwv + (a0 + a1) + (a2 + a3) + s_ghp[l], 0.0f));
                }
            } else if (wave == 2) {
                float xreg = s_x[buf][l];
                rlk<0, 32>(z0, z1, z2, z3, mreg, wz2);
                wait_flag(&s_fxc, t + 1);
                float xcv = s_xc[l];
                float a0 = 0, a1 = 0, a2 = 0, a3 = 0;
                rlk<0, 32>(a0, a1, a2, a3, xcv, wa);
                wait_flag(&s_fzhp, t + 1);
                float zh = bwv + (a0 + a1) + (a2 + a3) + s_zhp[l];
                float bt = s_bt[buf][l];
                float chat = bt * zh + (1.0f - bt) * s_xh[l];
                float ccv = fmaf(mreg, xreg, (1.0f - mreg) * chat);
                s_cc[l] = ccv;
                set_flag(&s_fcc, t + 1);
                out[(size_t)((n * 3 + 1) * Tt + t) * Dd + l] = zh;
                out[(size_t)((n * 3 + 2) * Tt + t) * Dd + l] = chat;
            } else {  // wave 3
                rlk<0, 32>(z0, z1, z2, z3, mreg, wz2);
                if (t + 1 < Tt) {                      // beta(t+1) in bubble
                    wait_flag(&s_fstage, t + 2);
                    float gxnb = s_gx[nbuf][l];
                    float a0 = 0, a1 = 0, a2 = 0, a3 = 0;
                    rlk<0, 64>(a0, a1, a2, a3, gxnb, wa);
                    wait_flag(&s_fbhp, t + 2);
                    s_bt[nbuf][l] = sigmoidf_(bwv + (a0 + a1) + (a2 + a3) + s_bhp[l]);
                }
            }
            // all primaries: cc part of z + combine + in-wave LSTM
            wait_flag(&s_fcc, t + 1);
            float ccv = s_cc[l];
            rlk<0, 64>(z0, z1, z2, z3, ccv, wz1);
            wait_flag(&s_fz[p], t + 1);
            float z = bl + (z0 + z1) + (z2 + z3) + s_zpart[p][l];
            float zi = __shfl(z, jl, 64);
            float zf = __shfl(z, 16 + jl, 64);
            float zg = __shfl(z, 32 + jl, 64);
            float zo = __shfl(z, 48 + jl, 64);
            c = sigmoidf_(zf) * c + sigmoidf_(zi) * tanhf_(zg);
            float hn = sigmoidf_(zo) * tanhf_(c);
            if (gate == 0) s_h[nbuf][(p << 4) + jl] = hn;
        }
        bar_lds();   // the ONLY barrier per step
    }

    // final prediction: sigmoid(h_last @ W_out + b_out)
    if (wave == 0) {
        float pr = s_h[Tt & 1][l] * wout;
#pragma unroll
        for (int off = 32; off > 0; off >>= 1) pr += __shfl_down(pr, off, 64);
        if (l == 0) out[(size_t)Nb * 3 * TD + n] = sigmoidf_(pr + bo);
    }
}

extern "C" void kernel_launch(void* const* d_in, const int* in_sizes, int n_in,
                              void* d_out, int out_size, void* d_ws, size_t ws_size,
                              hipStream_t stream) {
    (void)in_sizes; (void)n_in; (void)out_size; (void)d_ws; (void)ws_size;
    const float* inp    = (const float*)d_in[0];
    const float* W_hist = (const float*)d_in[1];
    const float* b_hist = (const float*)d_in[2];
    const float* W_feat = (const float*)d_in[3];
    const float* b_feat = (const float*)d_in[4];
    const float* W_gx   = (const float*)d_in[5];
    const float* b_gx   = (const float*)d_in[6];
    const float* W_gh   = (const float*)d_in[7];
    const float* b_gh   = (const float*)d_in[8];
    const float* W_beta = (const float*)d_in[9];
    const float* b_beta = (const float*)d_in[10];
    const float* W_lstm = (const float*)d_in[11];
    const float* U_lstm = (const float*)d_in[12];
    const float* b_lstm = (const float*)d_in[13];
    const float* W_out  = (const float*)d_in[14];
    const float* b_out  = (const float*)d_in[15];
    float* out = (float*)d_out;

    rits_kernel<<<dim3(Nb), dim3(512), 0, stream>>>(
        inp, W_hist, b_hist, W_feat, b_feat, W_gx, b_gx, W_gh, b_gh,
        W_beta, b_beta, W_lstm, U_lstm, b_lstm, W_out, b_out, out);
}